// Round 1
// baseline (483.477 us; speedup 1.0000x reference)
//
#include <hip/hip_runtime.h>
#include <hip/hip_bf16.h>
#include <stdint.h>

// B=32, L=4096, E=512(K), A=256(N).  M = B*L = 131072.
// ws layout: [0, 256KB) W_enc packed bf16; [256KB, 288KB) dec_full f32 [32][256];
//            [288KB, 800KB) scores f32 [32][4096]

typedef __attribute__((ext_vector_type(8))) short bf16x8;
typedef __attribute__((ext_vector_type(4))) float f32x4;

__device__ __forceinline__ unsigned short f32_to_bf16(float f) {
    union { float f; unsigned u; } v; v.f = f;
    unsigned u = v.u;
    u += 0x7fffu + ((u >> 16) & 1u);   // RNE
    return (unsigned short)(u >> 16);
}

__device__ __forceinline__ void async_load16(const void* g, void* l) {
    __builtin_amdgcn_global_load_lds(
        (const __attribute__((address_space(1))) unsigned int*)g,
        (__attribute__((address_space(3))) unsigned int*)l, 16, 0, 0);
}

// ---------------------------------------------------------------------------
// Prep: blocks 0..31 -> dec_full[b][a] = sum_h dh[b][h]*W_dec[h][a] + b_dec[a] + b_enc[a]
//       blocks 32..95 -> pack W_enc[E][A] fp32 -> bf16, layout [kb][chunk][n][j]
//       (kb = k/64, chunk = (k%64)/8, j = k%8) so main kernel B-staging is
//       lane-contiguous 16B cells for global_load_lds.
__global__ __launch_bounds__(256) void prep_kernel(
    const float* __restrict__ dh, const float* __restrict__ W_enc,
    const float* __restrict__ b_enc, const float* __restrict__ W_dec,
    const float* __restrict__ b_dec, unsigned short* __restrict__ Wp,
    float* __restrict__ dec_full)
{
    int t = threadIdx.x;
    if (blockIdx.x < 32) {
        int b = blockIdx.x;
        float acc = b_enc[t] + b_dec[t];
        for (int h = 0; h < 512; ++h)
            acc += dh[b * 512 + h] * W_dec[h * 256 + t];
        dec_full[b * 256 + t] = acc;
    } else {
        int tid = (blockIdx.x - 32) * 256 + t;
        #pragma unroll
        for (int i = 0; i < 8; ++i) {
            int d = tid + i * 16384;               // 0..131071
            int j = d & 7;
            int n = (d >> 3) & 255;
            int chunk = (d >> 11) & 7;
            int kb = d >> 14;
            int k = kb * 64 + chunk * 8 + j;
            Wp[d] = f32_to_bf16(W_enc[k * 256 + n]);
        }
    }
}

// ---------------------------------------------------------------------------
// Main: scores[r] = sum_a relu( (feat@W_enc)[r][a] + dec_full[b][a] ) * W_v[a]
// BM=128, BN=256(full A), BK=64. 256 threads = 4 waves, wave w owns cols [w*64, w*64+64).
__global__ __launch_bounds__(256) void score_kernel(
    const float* __restrict__ feat, const unsigned short* __restrict__ Wp,
    const float* __restrict__ dec_full, const float* __restrict__ W_v,
    float* __restrict__ scores)
{
    __shared__ unsigned short Alds[8192];    // 16 KB: cell(m,chunk)=16B @ m*64 + ((chunk^(m&7))*8) ushorts
    __shared__ unsigned short Blds[16384];   // 32 KB: cell(chunk,n)=16B @ (chunk*256+n)*8 ushorts
    __shared__ float red[4][128];

    const int t = threadIdx.x;
    const int lane = t & 63;
    const int wave = t >> 6;
    const int r0 = blockIdx.x * 128;
    const int b = r0 >> 12;                  // 4096 rows per batch, 128 | 4096

    // epilogue params: per lane, 4 columns a = wave*64 + ct*16 + (lane&15)
    float wv[4], dec[4];
    #pragma unroll
    for (int ct = 0; ct < 4; ++ct) {
        int a = wave * 64 + ct * 16 + (lane & 15);
        wv[ct] = W_v[a];
        dec[ct] = dec_full[b * 256 + a];
    }

    f32x4 acc[8][4];
    #pragma unroll
    for (int mt = 0; mt < 8; ++mt)
        #pragma unroll
        for (int ct = 0; ct < 4; ++ct)
            acc[mt][ct] = f32x4{0.f, 0.f, 0.f, 0.f};

    for (int ks = 0; ks < 8; ++ks) {
        // ---- B staging: 2048 cells of 16B, direct global->LDS
        #pragma unroll
        for (int q = 0; q < 8; ++q) {
            int c = q * 256 + wave * 64 + lane;
            async_load16(Wp + ks * 16384 + c * 8, Blds + c * 8);
        }
        // ---- A staging: 128 rows x 64 k fp32 -> bf16 (in-register cvt)
        float4 av[8];
        #pragma unroll
        for (int it = 0; it < 8; ++it) {
            int lin = it * 256 + t;
            int m = lin >> 4, kq = lin & 15;
            av[it] = *(const float4*)(feat + (size_t)(r0 + m) * 512 + ks * 64 + kq * 4);
        }
        #pragma unroll
        for (int it = 0; it < 8; ++it) {
            int lin = it * 256 + t;
            int m = lin >> 4, kq = lin & 15;
            int chunk = kq >> 1, jh = kq & 1;
            ushort4 w;
            w.x = f32_to_bf16(av[it].x);
            w.y = f32_to_bf16(av[it].y);
            w.z = f32_to_bf16(av[it].z);
            w.w = f32_to_bf16(av[it].w);
            int off = m * 64 + ((chunk ^ (m & 7)) * 8) + jh * 4;   // ushort units
            *(ushort4*)(Alds + off) = w;
        }
        __syncthreads();

        // ---- compute: two k-halves of 32
        #pragma unroll
        for (int kk = 0; kk < 2; ++kk) {
            int chunk = kk * 4 + (lane >> 4);
            bf16x8 bfr[4];
            #pragma unroll
            for (int ct = 0; ct < 4; ++ct) {
                int n = wave * 64 + ct * 16 + (lane & 15);
                bfr[ct] = *(const bf16x8*)(Blds + (chunk * 256 + n) * 8);
            }
            #pragma unroll
            for (int mt = 0; mt < 8; ++mt) {
                int m = mt * 16 + (lane & 15);
                bf16x8 afr = *(const bf16x8*)(Alds + m * 64 + ((chunk ^ (m & 7)) * 8));
                #pragma unroll
                for (int ct = 0; ct < 4; ++ct)
                    acc[mt][ct] = __builtin_amdgcn_mfma_f32_16x16x32_bf16(
                        afr, bfr[ct], acc[mt][ct], 0, 0, 0);
            }
        }
        __syncthreads();
    }

    // ---- epilogue: relu(acc + dec)*wv, reduce over 64 cols per wave
    // C layout: col = lane&15, row = (lane>>4)*4 + r
    #pragma unroll
    for (int mt = 0; mt < 8; ++mt) {
        #pragma unroll
        for (int r = 0; r < 4; ++r) {
            float p = 0.f;
            #pragma unroll
            for (int ct = 0; ct < 4; ++ct) {
                float v = acc[mt][ct][r] + dec[ct];
                v = v > 0.f ? v : 0.f;
                p += v * wv[ct];
            }
            p += __shfl_xor(p, 1);
            p += __shfl_xor(p, 2);
            p += __shfl_xor(p, 4);
            p += __shfl_xor(p, 8);
            if ((lane & 15) == 0)
                red[wave][mt * 16 + (lane >> 4) * 4 + r] = p;
        }
    }
    __syncthreads();
    if (t < 128)
        scores[r0 + t] = red[0][t] + red[1][t] + red[2][t] + red[3][t];
}

// ---------------------------------------------------------------------------
// Softmax over L per batch; also zeroes the output-region rows for wsum atomics.
__global__ __launch_bounds__(256) void softmax_kernel(
    const float* __restrict__ scores, float* __restrict__ out)
{
    __shared__ float sred[4];
    __shared__ float zred[4];
    int b = blockIdx.x, t = threadIdx.x;

    out[b * 512 + t] = 0.f;          // zero output[b][:]
    out[b * 512 + 256 + t] = 0.f;

    const float* s = scores + b * 4096;
    float vals[16];
    float m = -1e30f;
    #pragma unroll
    for (int i = 0; i < 16; ++i) { vals[i] = s[t + i * 256]; m = fmaxf(m, vals[i]); }
    #pragma unroll
    for (int o = 1; o < 64; o <<= 1) m = fmaxf(m, __shfl_xor(m, o));
    if ((t & 63) == 0) sred[t >> 6] = m;
    __syncthreads();
    m = fmaxf(fmaxf(sred[0], sred[1]), fmaxf(sred[2], sred[3]));

    float z = 0.f;
    #pragma unroll
    for (int i = 0; i < 16; ++i) { vals[i] = __expf(vals[i] - m); z += vals[i]; }
    #pragma unroll
    for (int o = 1; o < 64; o <<= 1) z += __shfl_xor(z, o);
    if ((t & 63) == 0) zred[t >> 6] = z;
    __syncthreads();
    z = zred[0] + zred[1] + zred[2] + zred[3];
    float inv = 1.f / z;
    #pragma unroll
    for (int i = 0; i < 16; ++i)
        out[16384 + b * 4096 + t + i * 256] = vals[i] * inv;
}

// ---------------------------------------------------------------------------
// output[b][e] = sum_l w[b][l] * feat[b][l][e].  Grid 32*16 blocks; each block
// does 256 l's; 256 threads: e4 = t&127 (float4 over E=512), lh = t>>7.
__global__ __launch_bounds__(256) void wsum_kernel(
    const float* __restrict__ feat, const float* __restrict__ outw,
    float* __restrict__ out)
{
    __shared__ float4 red2[128];
    int blk = blockIdx.x;
    int b = blk >> 4, lc = blk & 15;
    int t = threadIdx.x;
    int e4 = t & 127, lh = t >> 7;
    const float* w = outw + 16384 + b * 4096 + lc * 256;

    float4 acc = {0.f, 0.f, 0.f, 0.f};
    for (int i = 0; i < 128; ++i) {
        int l = i * 2 + lh;
        float wl = w[l];
        const float4 f = *(const float4*)(feat + (size_t)(b * 4096 + lc * 256 + l) * 512 + e4 * 4);
        acc.x += wl * f.x; acc.y += wl * f.y; acc.z += wl * f.z; acc.w += wl * f.w;
    }
    if (lh == 1) red2[e4] = acc;
    __syncthreads();
    if (lh == 0) {
        float4 o = red2[e4];
        atomicAdd(&out[b * 512 + e4 * 4 + 0], acc.x + o.x);
        atomicAdd(&out[b * 512 + e4 * 4 + 1], acc.y + o.y);
        atomicAdd(&out[b * 512 + e4 * 4 + 2], acc.z + o.z);
        atomicAdd(&out[b * 512 + e4 * 4 + 3], acc.w + o.w);
    }
}

extern "C" void kernel_launch(void* const* d_in, const int* in_sizes, int n_in,
                              void* d_out, int out_size, void* d_ws, size_t ws_size,
                              hipStream_t stream) {
    const float* feat  = (const float*)d_in[0];
    const float* dh    = (const float*)d_in[1];
    const float* W_enc = (const float*)d_in[2];
    const float* b_enc = (const float*)d_in[3];
    const float* W_dec = (const float*)d_in[4];
    const float* b_dec = (const float*)d_in[5];
    const float* W_v   = (const float*)d_in[6];
    // d_in[7] = b_v: softmax shift-invariant, unused.

    unsigned short* Wp = (unsigned short*)d_ws;
    float* dec_full = (float*)((char*)d_ws + 262144);
    float* scores   = (float*)((char*)d_ws + 294912);
    float* out      = (float*)d_out;

    prep_kernel<<<96, 256, 0, stream>>>(dh, W_enc, b_enc, W_dec, b_dec, Wp, dec_full);
    score_kernel<<<1024, 256, 0, stream>>>(feat, Wp, dec_full, W_v, scores);
    softmax_kernel<<<32, 256, 0, stream>>>(scores, out);
    wsum_kernel<<<512, 256, 0, stream>>>(feat, out, out);
}

// Round 2
// 453.296 us; speedup vs baseline: 1.0666x; 1.0666x over previous
//
#include <hip/hip_runtime.h>
#include <hip/hip_bf16.h>
#include <stdint.h>

// B=32, L=4096, E=512(K), A=256(N).  M = B*L = 131072.
// ws layout: [0, 256KB) W_enc packed bf16; [256KB, 288KB) dec_full f32 [32][256];
//            [288KB, 800KB) scores f32 [32][4096]

typedef __attribute__((ext_vector_type(8))) short bf16x8;
typedef __attribute__((ext_vector_type(4))) float f32x4;

__device__ __forceinline__ unsigned short f32_to_bf16(float f) {
    union { float f; unsigned u; } v; v.f = f;
    unsigned u = v.u;
    u += 0x7fffu + ((u >> 16) & 1u);   // RNE
    return (unsigned short)(u >> 16);
}

__device__ __forceinline__ void async_load16(const void* g, void* l) {
    __builtin_amdgcn_global_load_lds(
        (const __attribute__((address_space(1))) unsigned int*)g,
        (__attribute__((address_space(3))) unsigned int*)l, 16, 0, 0);
}

// ---------------------------------------------------------------------------
// Prep: blocks 0..31 -> dec_full[b][a] = sum_h dh[b][h]*W_dec[h][a] + b_dec[a] + b_enc[a]
//       blocks 32..95 -> pack W_enc[E][A] fp32 -> bf16, layout [kb][chunk][n][j]
__global__ __launch_bounds__(256) void prep_kernel(
    const float* __restrict__ dh, const float* __restrict__ W_enc,
    const float* __restrict__ b_enc, const float* __restrict__ W_dec,
    const float* __restrict__ b_dec, unsigned short* __restrict__ Wp,
    float* __restrict__ dec_full)
{
    int t = threadIdx.x;
    if (blockIdx.x < 32) {
        int b = blockIdx.x;
        float a0 = 0.f, a1 = 0.f;
        #pragma unroll 4
        for (int h = 0; h < 512; h += 2) {
            a0 += dh[b * 512 + h] * W_dec[h * 256 + t];
            a1 += dh[b * 512 + h + 1] * W_dec[(h + 1) * 256 + t];
        }
        dec_full[b * 256 + t] = a0 + a1 + b_enc[t] + b_dec[t];
    } else {
        int tid = (blockIdx.x - 32) * 256 + t;
        #pragma unroll
        for (int i = 0; i < 8; ++i) {
            int d = tid + i * 16384;               // 0..131071
            int j = d & 7;
            int n = (d >> 3) & 255;
            int chunk = (d >> 11) & 7;
            int kb = d >> 14;
            int k = kb * 64 + chunk * 8 + j;
            Wp[d] = f32_to_bf16(W_enc[k * 256 + n]);
        }
    }
}

// ---------------------------------------------------------------------------
// Main: scores[r] = sum_a relu( (feat@W_enc)[r][a] + dec_full[b][a] ) * W_v[a]
// BM=128, BN=256(full A), BK=64. 256 threads = 4 waves, wave w owns cols [w*64, w*64+64).
// __launch_bounds__(256,2): cap VGPR at 256 -> guaranteed 2 blocks/CU.
__global__ __launch_bounds__(256, 2) void score_kernel(
    const float* __restrict__ feat, const unsigned short* __restrict__ Wp,
    const float* __restrict__ dec_full, const float* __restrict__ W_v,
    float* __restrict__ scores)
{
    __shared__ unsigned short Alds[8192];    // 16 KB: cell(m,chunk)=8B @ m*64 + ((chunk^(m&7))*8) ushorts
    __shared__ unsigned short Blds[16384];   // 32 KB: cell(chunk,n)=16B @ (chunk*256+n)*8 ushorts
    __shared__ float red[4][128];

    const int t = threadIdx.x;
    const int lane = t & 63;
    const int wave = t >> 6;
    const int r0 = blockIdx.x * 128;
    const int b = r0 >> 12;                  // 4096 rows per batch, 128 | 4096

    float wv[4], dec[4];
    #pragma unroll
    for (int ct = 0; ct < 4; ++ct) {
        int a = wave * 64 + ct * 16 + (lane & 15);
        wv[ct] = W_v[a];
        dec[ct] = dec_full[b * 256 + a];
    }

    f32x4 acc[8][4];
    #pragma unroll
    for (int mt = 0; mt < 8; ++mt)
        #pragma unroll
        for (int ct = 0; ct < 4; ++ct)
            acc[mt][ct] = f32x4{0.f, 0.f, 0.f, 0.f};

    for (int ks = 0; ks < 8; ++ks) {
        // ---- B staging: 2048 cells of 16B, direct global->LDS
        #pragma unroll
        for (int q = 0; q < 8; ++q) {
            int c = q * 256 + wave * 64 + lane;
            async_load16(Wp + ks * 16384 + c * 8, Blds + c * 8);
        }
        // ---- A staging: 128 rows x 64 k, fp32 load -> bf16 cvt -> LDS (fused)
        #pragma unroll
        for (int it = 0; it < 8; ++it) {
            int lin = it * 256 + t;
            int m = lin >> 4, kq = lin & 15;
            float4 a = *(const float4*)(feat + (size_t)(r0 + m) * 512 + ks * 64 + kq * 4);
            ushort4 w;
            w.x = f32_to_bf16(a.x);
            w.y = f32_to_bf16(a.y);
            w.z = f32_to_bf16(a.z);
            w.w = f32_to_bf16(a.w);
            int chunk = kq >> 1, jh = kq & 1;
            int off = m * 64 + ((chunk ^ (m & 7)) * 8) + jh * 4;   // ushort units
            *(ushort4*)(Alds + off) = w;
        }
        __syncthreads();

        // ---- compute: two k-halves of 32
        #pragma unroll
        for (int kk = 0; kk < 2; ++kk) {
            int chunk = kk * 4 + (lane >> 4);
            bf16x8 bfr[4];
            #pragma unroll
            for (int ct = 0; ct < 4; ++ct) {
                int n = wave * 64 + ct * 16 + (lane & 15);
                bfr[ct] = *(const bf16x8*)(Blds + (chunk * 256 + n) * 8);
            }
            #pragma unroll
            for (int mt = 0; mt < 8; ++mt) {
                int m = mt * 16 + (lane & 15);
                bf16x8 afr = *(const bf16x8*)(Alds + m * 64 + ((chunk ^ (m & 7)) * 8));
                #pragma unroll
                for (int ct = 0; ct < 4; ++ct)
                    acc[mt][ct] = __builtin_amdgcn_mfma_f32_16x16x32_bf16(
                        afr, bfr[ct], acc[mt][ct], 0, 0, 0);
            }
        }
        __syncthreads();
    }

    // ---- epilogue: relu(acc + dec)*wv, reduce over 64 cols per wave
    // C layout: col = lane&15, row = (lane>>4)*4 + r
    #pragma unroll
    for (int mt = 0; mt < 8; ++mt) {
        #pragma unroll
        for (int r = 0; r < 4; ++r) {
            float p = 0.f;
            #pragma unroll
            for (int ct = 0; ct < 4; ++ct) {
                float v = acc[mt][ct][r] + dec[ct];
                v = v > 0.f ? v : 0.f;
                p += v * wv[ct];
            }
            p += __shfl_xor(p, 1);
            p += __shfl_xor(p, 2);
            p += __shfl_xor(p, 4);
            p += __shfl_xor(p, 8);
            if ((lane & 15) == 0)
                red[wave][mt * 16 + (lane >> 4) * 4 + r] = p;
        }
    }
    __syncthreads();
    if (t < 128)
        scores[r0 + t] = red[0][t] + red[1][t] + red[2][t] + red[3][t];
}

// ---------------------------------------------------------------------------
// Softmax over L per batch; also zeroes the output-region rows for wsum atomics.
__global__ __launch_bounds__(256) void softmax_kernel(
    const float* __restrict__ scores, float* __restrict__ out)
{
    __shared__ float sred[4];
    __shared__ float zred[4];
    int b = blockIdx.x, t = threadIdx.x;

    out[b * 512 + t] = 0.f;          // zero output[b][:]
    out[b * 512 + 256 + t] = 0.f;

    const float* s = scores + b * 4096;
    float vals[16];
    float m = -1e30f;
    #pragma unroll
    for (int i = 0; i < 16; ++i) { vals[i] = s[t + i * 256]; m = fmaxf(m, vals[i]); }
    #pragma unroll
    for (int o = 1; o < 64; o <<= 1) m = fmaxf(m, __shfl_xor(m, o));
    if ((t & 63) == 0) sred[t >> 6] = m;
    __syncthreads();
    m = fmaxf(fmaxf(sred[0], sred[1]), fmaxf(sred[2], sred[3]));

    float z = 0.f;
    #pragma unroll
    for (int i = 0; i < 16; ++i) { vals[i] = __expf(vals[i] - m); z += vals[i]; }
    #pragma unroll
    for (int o = 1; o < 64; o <<= 1) z += __shfl_xor(z, o);
    if ((t & 63) == 0) zred[t >> 6] = z;
    __syncthreads();
    z = zred[0] + zred[1] + zred[2] + zred[3];
    float inv = 1.f / z;
    #pragma unroll
    for (int i = 0; i < 16; ++i)
        out[16384 + b * 4096 + t + i * 256] = vals[i] * inv;
}

// ---------------------------------------------------------------------------
// output[b][e] = sum_l w[b][l] * feat[b][l][e].  Grid 32*32 blocks; each block
// does 128 l's; 256 threads: e4 = t&127 (float4 over E=512), lh = t>>7.
__global__ __launch_bounds__(256) void wsum_kernel(
    const float* __restrict__ feat, const float* __restrict__ outw,
    float* __restrict__ out)
{
    __shared__ float4 red2[128];
    int blk = blockIdx.x;
    int b = blk >> 5, lc = blk & 31;
    int t = threadIdx.x;
    int e4 = t & 127, lh = t >> 7;
    const float* w = outw + 16384 + b * 4096 + lc * 128;

    float4 acc = {0.f, 0.f, 0.f, 0.f};
    #pragma unroll 8
    for (int i = 0; i < 64; ++i) {
        int l = i * 2 + lh;
        float wl = w[l];
        const float4 f = *(const float4*)(feat + (size_t)(b * 4096 + lc * 128 + l) * 512 + e4 * 4);
        acc.x += wl * f.x; acc.y += wl * f.y; acc.z += wl * f.z; acc.w += wl * f.w;
    }
    if (lh == 1) red2[e4] = acc;
    __syncthreads();
    if (lh == 0) {
        float4 o = red2[e4];
        atomicAdd(&out[b * 512 + e4 * 4 + 0], acc.x + o.x);
        atomicAdd(&out[b * 512 + e4 * 4 + 1], acc.y + o.y);
        atomicAdd(&out[b * 512 + e4 * 4 + 2], acc.z + o.z);
        atomicAdd(&out[b * 512 + e4 * 4 + 3], acc.w + o.w);
    }
}

extern "C" void kernel_launch(void* const* d_in, const int* in_sizes, int n_in,
                              void* d_out, int out_size, void* d_ws, size_t ws_size,
                              hipStream_t stream) {
    const float* feat  = (const float*)d_in[0];
    const float* dh    = (const float*)d_in[1];
    const float* W_enc = (const float*)d_in[2];
    const float* b_enc = (const float*)d_in[3];
    const float* W_dec = (const float*)d_in[4];
    const float* b_dec = (const float*)d_in[5];
    const float* W_v   = (const float*)d_in[6];
    // d_in[7] = b_v: softmax shift-invariant, unused.

    unsigned short* Wp = (unsigned short*)d_ws;
    float* dec_full = (float*)((char*)d_ws + 262144);
    float* scores   = (float*)((char*)d_ws + 294912);
    float* out      = (float*)d_out;

    prep_kernel<<<96, 256, 0, stream>>>(dh, W_enc, b_enc, W_dec, b_dec, Wp, dec_full);
    score_kernel<<<1024, 256, 0, stream>>>(feat, Wp, dec_full, W_v, scores);
    softmax_kernel<<<32, 256, 0, stream>>>(scores, out);
    wsum_kernel<<<1024, 256, 0, stream>>>(feat, out, out);
}

// Round 3
// 447.985 us; speedup vs baseline: 1.0792x; 1.0119x over previous
//
#include <hip/hip_runtime.h>
#include <hip/hip_bf16.h>
#include <stdint.h>

// B=32, L=4096, E=512(K), A=256(N).  M = B*L = 131072.
// ws layout:
//   [0,      262144)  Wp       bf16 W_enc packed [kb][chunk][n][j]
//   [262144, 294912)  dec_full f32 [32][256]
//   [294912, 819200)  scores   f32 [32][4096]
//   [819200, 823296)  m_c      f32 [1024]   per-block score max
//   [823296, 823552)  MZ       f32 [64]     M[32], Z[32]
//   [1048576,3145728) o_part   f32 [1024][512] per-block weighted-feat partials

typedef __attribute__((ext_vector_type(8))) short bf16x8;
typedef __attribute__((ext_vector_type(4))) float f32x4;

__device__ __forceinline__ unsigned short f32_to_bf16(float f) {
    union { float f; unsigned u; } v; v.f = f;
    unsigned u = v.u;
    u += 0x7fffu + ((u >> 16) & 1u);   // RNE
    return (unsigned short)(u >> 16);
}

__device__ __forceinline__ void async_load16(const void* g, void* l) {
    __builtin_amdgcn_global_load_lds(
        (const __attribute__((address_space(1))) unsigned int*)g,
        (__attribute__((address_space(3))) unsigned int*)l, 16, 0, 0);
}

// ---------------------------------------------------------------------------
// Prep: blocks 0..31 -> dec_full[b][a]; blocks 32..95 -> pack W_enc fp32->bf16
__global__ __launch_bounds__(256) void prep_kernel(
    const float* __restrict__ dh, const float* __restrict__ W_enc,
    const float* __restrict__ b_enc, const float* __restrict__ W_dec,
    const float* __restrict__ b_dec, unsigned short* __restrict__ Wp,
    float* __restrict__ dec_full)
{
    int t = threadIdx.x;
    if (blockIdx.x < 32) {
        int b = blockIdx.x;
        float a0 = 0.f, a1 = 0.f, a2 = 0.f, a3 = 0.f;
        #pragma unroll 2
        for (int h = 0; h < 512; h += 4) {
            a0 += dh[b * 512 + h + 0] * W_dec[(h + 0) * 256 + t];
            a1 += dh[b * 512 + h + 1] * W_dec[(h + 1) * 256 + t];
            a2 += dh[b * 512 + h + 2] * W_dec[(h + 2) * 256 + t];
            a3 += dh[b * 512 + h + 3] * W_dec[(h + 3) * 256 + t];
        }
        dec_full[b * 256 + t] = (a0 + a1) + (a2 + a3) + b_enc[t] + b_dec[t];
    } else {
        int tid = (blockIdx.x - 32) * 256 + t;
        #pragma unroll
        for (int i = 0; i < 8; ++i) {
            int d = tid + i * 16384;               // 0..131071
            int j = d & 7;
            int n = (d >> 3) & 255;
            int chunk = (d >> 11) & 7;
            int kb = d >> 14;
            int k = kb * 64 + chunk * 8 + j;
            Wp[d] = f32_to_bf16(W_enc[k * 256 + n]);
        }
    }
}

// ---------------------------------------------------------------------------
// Fused: GEMM scores + block-local softmax partial + weighted-feat partial.
// BM=128, BN=256(full A), BK=64; 256 threads = 4 waves.
__global__ __launch_bounds__(256, 2) void score_kernel(
    const float* __restrict__ feat, const unsigned short* __restrict__ Wp,
    const float* __restrict__ dec_full, const float* __restrict__ W_v,
    float* __restrict__ scores, float* __restrict__ m_c,
    float* __restrict__ o_part)
{
    __shared__ unsigned short Alds[8192];    // 16 KB swizzled A tile
    __shared__ unsigned short Blds[16384];   // 32 KB B tile
    __shared__ float red[4][128];
    __shared__ float sblk[128];
    __shared__ float wexp[128];
    __shared__ float mshr;
    __shared__ float red2x[128], red2y[128], red2z[128], red2w[128];

    const int t = threadIdx.x;
    const int lane = t & 63;
    const int wave = t >> 6;
    const int r0 = blockIdx.x * 128;
    const int b = r0 >> 12;

    float wv[4], dec[4];
    #pragma unroll
    for (int ct = 0; ct < 4; ++ct) {
        int a = wave * 64 + ct * 16 + (lane & 15);
        wv[ct] = W_v[a];
        dec[ct] = dec_full[b * 256 + a];
    }

    f32x4 acc[8][4];
    #pragma unroll
    for (int mt = 0; mt < 8; ++mt)
        #pragma unroll
        for (int ct = 0; ct < 4; ++ct)
            acc[mt][ct] = f32x4{0.f, 0.f, 0.f, 0.f};

    // prologue: prefetch feat tile ks=0 into registers
    float4 av[8];
    #pragma unroll
    for (int it = 0; it < 8; ++it) {
        int lin = it * 256 + t;
        int m = lin >> 4, kq = lin & 15;
        av[it] = *(const float4*)(feat + (size_t)(r0 + m) * 512 + kq * 4);
    }

    for (int ks = 0; ks < 8; ++ks) {
        // B staging: async global->LDS (L2-resident Wp)
        #pragma unroll
        for (int q = 0; q < 8; ++q) {
            int c = q * 256 + wave * 64 + lane;
            async_load16(Wp + ks * 16384 + c * 8, Blds + c * 8);
        }
        // A staging: cvt prefetched regs -> LDS (swizzled)
        #pragma unroll
        for (int it = 0; it < 8; ++it) {
            int lin = it * 256 + t;
            int m = lin >> 4, kq = lin & 15;
            ushort4 w;
            w.x = f32_to_bf16(av[it].x);
            w.y = f32_to_bf16(av[it].y);
            w.z = f32_to_bf16(av[it].z);
            w.w = f32_to_bf16(av[it].w);
            int chunk = kq >> 1, jh = kq & 1;
            *(ushort4*)(Alds + m * 64 + ((chunk ^ (m & 7)) * 8) + jh * 4) = w;
        }
        __syncthreads();
        // prefetch NEXT feat tile: in flight during MFMA phase
        if (ks < 7) {
            #pragma unroll
            for (int it = 0; it < 8; ++it) {
                int lin = it * 256 + t;
                int m = lin >> 4, kq = lin & 15;
                av[it] = *(const float4*)(feat + (size_t)(r0 + m) * 512 + (ks + 1) * 64 + kq * 4);
            }
        }
        // compute
        #pragma unroll
        for (int kk = 0; kk < 2; ++kk) {
            int chunk = kk * 4 + (lane >> 4);
            bf16x8 bfr[4];
            #pragma unroll
            for (int ct = 0; ct < 4; ++ct) {
                int n = wave * 64 + ct * 16 + (lane & 15);
                bfr[ct] = *(const bf16x8*)(Blds + (chunk * 256 + n) * 8);
            }
            #pragma unroll
            for (int mt = 0; mt < 8; ++mt) {
                int m = mt * 16 + (lane & 15);
                bf16x8 afr = *(const bf16x8*)(Alds + m * 64 + ((chunk ^ (m & 7)) * 8));
                #pragma unroll
                for (int ct = 0; ct < 4; ++ct)
                    acc[mt][ct] = __builtin_amdgcn_mfma_f32_16x16x32_bf16(
                        afr, bfr[ct], acc[mt][ct], 0, 0, 0);
            }
        }
        __syncthreads();
    }

    // ---- score epilogue: relu(acc+dec)*wv, 16-lane butterfly, 4-wave sum
    #pragma unroll
    for (int mt = 0; mt < 8; ++mt) {
        #pragma unroll
        for (int r = 0; r < 4; ++r) {
            float p = 0.f;
            #pragma unroll
            for (int ct = 0; ct < 4; ++ct) {
                float v = acc[mt][ct][r] + dec[ct];
                v = v > 0.f ? v : 0.f;
                p += v * wv[ct];
            }
            p += __shfl_xor(p, 1);
            p += __shfl_xor(p, 2);
            p += __shfl_xor(p, 4);
            p += __shfl_xor(p, 8);
            if ((lane & 15) == 0)
                red[wave][mt * 16 + (lane >> 4) * 4 + r] = p;
        }
    }
    __syncthreads();
    if (t < 128) {
        float v = red[0][t] + red[1][t] + red[2][t] + red[3][t];
        sblk[t] = v;
        scores[r0 + t] = v;
    }
    __syncthreads();
    // block max over the 128 scores
    if (t < 64) {
        float m = fmaxf(sblk[t], sblk[t + 64]);
        #pragma unroll
        for (int o = 1; o < 64; o <<= 1) m = fmaxf(m, __shfl_xor(m, o));
        if (t == 0) mshr = m;
    }
    __syncthreads();
    float mb = mshr;
    if (t < 128) wexp[t] = __expf(sblk[t] - mb);
    __syncthreads();

    // ---- partial weighted-feature sum: o_c[e] = sum_l wexp[l]*feat[r0+l][e]
    // tile is L3-hot (just streamed by the GEMM above)
    int e4 = t & 127, lh = t >> 7;
    float ax = 0.f, ay = 0.f, az = 0.f, aw = 0.f;
    #pragma unroll 8
    for (int i = 0; i < 64; ++i) {
        int l = i * 2 + lh;
        float wl = wexp[l];
        const float4 f = *(const float4*)(feat + (size_t)(r0 + l) * 512 + e4 * 4);
        ax += wl * f.x; ay += wl * f.y; az += wl * f.z; aw += wl * f.w;
    }
    if (lh) { red2x[e4] = ax; red2y[e4] = ay; red2z[e4] = az; red2w[e4] = aw; }
    __syncthreads();
    if (!lh) {
        float4 r;
        r.x = ax + red2x[e4]; r.y = ay + red2y[e4];
        r.z = az + red2z[e4]; r.w = aw + red2w[e4];
        *(float4*)(o_part + (size_t)blockIdx.x * 512 + e4 * 4) = r;
        if (t == 0) m_c[blockIdx.x] = mb;
    }
}

// ---------------------------------------------------------------------------
// Softmax over L per batch; writes attn weights + M[b], Z[b].
__global__ __launch_bounds__(256) void softmax_kernel(
    const float* __restrict__ scores, float* __restrict__ out,
    float* __restrict__ MZ)
{
    __shared__ float sred[4];
    __shared__ float zred[4];
    int b = blockIdx.x, t = threadIdx.x;

    const float* s = scores + b * 4096;
    float vals[16];
    float m = -1e30f;
    #pragma unroll
    for (int i = 0; i < 16; ++i) { vals[i] = s[t + i * 256]; m = fmaxf(m, vals[i]); }
    #pragma unroll
    for (int o = 1; o < 64; o <<= 1) m = fmaxf(m, __shfl_xor(m, o));
    if ((t & 63) == 0) sred[t >> 6] = m;
    __syncthreads();
    m = fmaxf(fmaxf(sred[0], sred[1]), fmaxf(sred[2], sred[3]));

    float z = 0.f;
    #pragma unroll
    for (int i = 0; i < 16; ++i) { vals[i] = __expf(vals[i] - m); z += vals[i]; }
    #pragma unroll
    for (int o = 1; o < 64; o <<= 1) z += __shfl_xor(z, o);
    if ((t & 63) == 0) zred[t >> 6] = z;
    __syncthreads();
    z = zred[0] + zred[1] + zred[2] + zred[3];
    float inv = 1.f / z;
    #pragma unroll
    for (int i = 0; i < 16; ++i)
        out[16384 + b * 4096 + t + i * 256] = vals[i] * inv;
    if (t == 0) { MZ[b] = m; MZ[32 + b] = z; }
}

// ---------------------------------------------------------------------------
// Combine: out[b][e] = (1/Z_b) * sum_c exp(m_c - M_b) * o_part[b*32+c][e]
__global__ __launch_bounds__(256) void combine_kernel(
    const float* __restrict__ o_part, const float* __restrict__ m_c,
    const float* __restrict__ MZ, float* __restrict__ out)
{
    __shared__ float sc[32];
    int b = blockIdx.x, t = threadIdx.x;
    if (t < 32) sc[t] = __expf(m_c[b * 32 + t] - MZ[b]) * (1.f / MZ[32 + b]);
    __syncthreads();
    float a0 = 0.f, a1 = 0.f;
    #pragma unroll 8
    for (int c = 0; c < 32; ++c) {
        const float2 v = *(const float2*)(o_part + (size_t)(b * 32 + c) * 512 + t * 2);
        a0 += sc[c] * v.x; a1 += sc[c] * v.y;
    }
    float2 r; r.x = a0; r.y = a1;
    *(float2*)(out + b * 512 + t * 2) = r;
}

extern "C" void kernel_launch(void* const* d_in, const int* in_sizes, int n_in,
                              void* d_out, int out_size, void* d_ws, size_t ws_size,
                              hipStream_t stream) {
    const float* feat  = (const float*)d_in[0];
    const float* dh    = (const float*)d_in[1];
    const float* W_enc = (const float*)d_in[2];
    const float* b_enc = (const float*)d_in[3];
    const float* W_dec = (const float*)d_in[4];
    const float* b_dec = (const float*)d_in[5];
    const float* W_v   = (const float*)d_in[6];
    // d_in[7] = b_v: softmax shift-invariant, unused.

    unsigned short* Wp = (unsigned short*)d_ws;
    float* dec_full = (float*)((char*)d_ws + 262144);
    float* scores   = (float*)((char*)d_ws + 294912);
    float* m_c      = (float*)((char*)d_ws + 819200);
    float* MZ       = (float*)((char*)d_ws + 823296);
    float* o_part   = (float*)((char*)d_ws + 1048576);
    float* out      = (float*)d_out;

    prep_kernel<<<96, 256, 0, stream>>>(dh, W_enc, b_enc, W_dec, b_dec, Wp, dec_full);
    score_kernel<<<1024, 256, 0, stream>>>(feat, Wp, dec_full, W_v, scores, m_c, o_part);
    softmax_kernel<<<32, 256, 0, stream>>>(scores, out, MZ);
    combine_kernel<<<32, 256, 0, stream>>>(o_part, m_c, MZ, out);
}